// Round 16
// baseline (777.954 us; speedup 1.0000x reference)
//
#include <hip/hip_runtime.h>
#include <hip/hip_fp16.h>
#include <math.h>

#define NN 25000
#define EE 400000
#define HH 64
#define NHEAD 4
#define SDIM 16
#define EFDIM 8
#define KHOP 2
#define MIN 168   // 2H + 2S + EF
#define WID 128
#define GIN 192
#define KP 96     // padded K for node-proj GEMM (80 -> 96)
#define CROW 320  // cAB row stride (ushort): 256 f16 proj + 64 bf16 hn copy

typedef __attribute__((ext_vector_type(8))) short bf16x8;
typedef __attribute__((ext_vector_type(4))) float f32x4;
typedef unsigned short ushortT;
typedef unsigned int uintT;

__device__ __forceinline__ float wave_sum64(float v) {
#pragma unroll
  for (int m = 1; m <= 32; m <<= 1) v += __shfl_xor(v, m, 64);
  return v;
}

__device__ __forceinline__ ushortT f2b(float f) {
  uintT u = __float_as_uint(f);
  return (ushortT)((u + 0x7FFFu + ((u >> 16) & 1u)) >> 16);
}
__device__ __forceinline__ float b2f(ushortT h) {
  return __uint_as_float(((uintT)h) << 16);
}

union U4H8 {
  uint4 u;
  __half2 h[4];
};

// packed-f16 ReLU via sign-bit mask (no __hmax2 on ROCm 7.2)
__device__ __forceinline__ __half2 relu2(__half2 v) {
  union { __half2 h; uintT u; } x;
  x.h = v;
  uintT mask = ((x.u & 0x80008000u) >> 15) * 0xFFFFu;
  x.u &= ~mask;
  return x.h;
}

// ---------------- CSR build (both directions in one pass) ----------------
__global__ void k_histo2(const int* __restrict__ src, const int* __restrict__ dst,
                         int* __restrict__ cnt_s, int* __restrict__ cnt_d) {
  int e = blockIdx.x * 256 + threadIdx.x;
  if (e < EE) {
    atomicAdd(&cnt_d[dst[e]], 1);
    atomicAdd(&cnt_s[src[e]], 1);
  }
}

__global__ void k_scan2(const int* __restrict__ cnt_d, const int* __restrict__ cnt_s,
                        int* __restrict__ rp_d, int* __restrict__ rp_s) {
  const int* cnt = blockIdx.x ? cnt_s : cnt_d;
  int* rp = blockIdx.x ? rp_s : rp_d;
  __shared__ int part[1024];
  int t = threadIdx.x;
  const int CH = (NN + 1023) / 1024;
  int base = t * CH;
  int s = 0;
  for (int i = 0; i < CH; ++i) {
    int j = base + i;
    if (j < NN) s += cnt[j];
  }
  part[t] = s;
  __syncthreads();
  for (int off = 1; off < 1024; off <<= 1) {
    int v = (t >= off) ? part[t - off] : 0;
    __syncthreads();
    part[t] += v;
    __syncthreads();
  }
  int run = (t == 0) ? 0 : part[t - 1];
  for (int i = 0; i < CH; ++i) {
    int j = base + i;
    if (j < NN) { rp[j] = run; run += cnt[j]; }
  }
  if (t == 1023) rp[NN] = run;
}

__global__ void k_scatter2(const int* __restrict__ src, const int* __restrict__ dst,
                           const int* __restrict__ rp_s, const int* __restrict__ rp_d,
                           int* __restrict__ cur_s, int* __restrict__ cur_d,
                           int* __restrict__ eid_s, int* __restrict__ eid_d) {
  int e = blockIdx.x * 256 + threadIdx.x;
  if (e < EE) {
    int nd = dst[e];
    int pd = atomicAdd(&cur_d[nd], 1);
    eid_d[rp_d[nd] + pd] = e;
    int ns = src[e];
    int ps = atomicAdd(&cur_s[ns], 1);
    eid_s[rp_s[ns] + ps] = e;
  }
}

// wave-parallel bitonic sort of each segment (deterministic ascending order)
__global__ __launch_bounds__(256) void k_sortseg2(const int* __restrict__ rp_d,
                                                  const int* __restrict__ rp_s,
                                                  int* __restrict__ eid_d,
                                                  int* __restrict__ eid_s) {
  int gw = blockIdx.x * 4 + (threadIdx.x >> 6);
  int lane = threadIdx.x & 63;
  if (gw >= 2 * NN) return;
  const int* rp = (gw < NN) ? rp_d : rp_s;
  int* eids = (gw < NN) ? eid_d : eid_s;
  int node = (gw < NN) ? gw : gw - NN;
  int beg = rp[node], end = rp[node + 1];
  int deg = end - beg;
  if (deg <= 1) return;
  if (deg <= 64) {
    int v = (lane < deg) ? eids[beg + lane] : 0x7fffffff;
#pragma unroll
    for (int k = 2; k <= 64; k <<= 1) {
#pragma unroll
      for (int j = k >> 1; j > 0; j >>= 1) {
        int other = __shfl_xor(v, j, 64);
        bool takeMin = (((lane & k) == 0) == ((lane & j) == 0));
        v = takeMin ? min(v, other) : max(v, other);
      }
    }
    if (lane < deg) eids[beg + lane] = v;
  } else if (lane == 0) {
    for (int i = beg + 1; i < end; ++i) {
      int v = eids[i];
      int j = i - 1;
      while (j >= beg && eids[j] > v) { eids[j + 1] = eids[j]; --j; }
      eids[j + 1] = v;
    }
  }
}

// pos[ii] = {e, other_node, owner_node, 0}; position-ordered ef packed f16 (uint4)
__global__ void k_mkpos2(const int* __restrict__ eid_d, const int* __restrict__ eid_s,
                         const int* __restrict__ src, const int* __restrict__ dst,
                         const float* __restrict__ ef, int4* __restrict__ pos_f,
                         int4* __restrict__ pos_r, uint4* __restrict__ efh_f,
                         uint4* __restrict__ efh_r) {
  int i = blockIdx.x * 256 + threadIdx.x;
  if (i >= EE) return;
  int e1 = eid_d[i];
  pos_f[i] = make_int4(e1, src[e1], dst[e1], 0);
  int e2 = eid_s[i];
  pos_r[i] = make_int4(e2, dst[e2], src[e2], 0);
  {
    float4 a0 = *(const float4*)(ef + (size_t)e1 * EFDIM);
    float4 a1 = *(const float4*)(ef + (size_t)e1 * EFDIM + 4);
    U4H8 u;
    u.h[0] = __floats2half2_rn(a0.x, a0.y);
    u.h[1] = __floats2half2_rn(a0.z, a0.w);
    u.h[2] = __floats2half2_rn(a1.x, a1.y);
    u.h[3] = __floats2half2_rn(a1.z, a1.w);
    efh_f[i] = u.u;
  }
  {
    float4 b0 = *(const float4*)(ef + (size_t)e2 * EFDIM);
    float4 b1 = *(const float4*)(ef + (size_t)e2 * EFDIM + 4);
    U4H8 u;
    u.h[0] = __floats2half2_rn(b0.x, b0.y);
    u.h[1] = __floats2half2_rn(b0.z, b0.w);
    u.h[2] = __floats2half2_rn(b1.x, b1.y);
    u.h[3] = __floats2half2_rn(b1.z, b1.w);
    efh_r[i] = u.u;
  }
}

// weight repack: pAB bf16[256][96] + w1e2 half2[8][64] + w22 half2[4][64] + proj bf16[64][64]
#define PACKN (256 * KP + 512 + 256 + 4096)
__global__ void k_pack_bf(const float* __restrict__ fw1, const float* __restrict__ rw1,
                          const float* __restrict__ fw2, const float* __restrict__ rw2,
                          const float* __restrict__ fpj, const float* __restrict__ rpj,
                          ushortT* __restrict__ pAB_all, __half2* __restrict__ w1e2_all,
                          __half2* __restrict__ w22_all, ushortT* __restrict__ pj_all) {
  int y = blockIdx.y;
  const float* w1 = (y < 2) ? fw1 + (size_t)y * WID * MIN
                            : rw1 + (size_t)(y - 2) * WID * MIN;
  const float* w2 = (y < 2) ? fw2 + (size_t)y * NHEAD * WID
                            : rw2 + (size_t)(y - 2) * NHEAD * WID;
  const float* pj = (y < 2) ? fpj + (size_t)y * HH * HH
                            : rpj + (size_t)(y - 2) * HH * HH;
  int i = blockIdx.x * 256 + threadIdx.x;
  if (i < 256 * KP) {
    int j = i / KP, k = i % KP;
    float v = 0.f;
    if (k < 80) {
      int row = (j < 128) ? j : j - 128;
      int col = (j < 128) ? (k < 64 ? k : k + 64) : (k < 64 ? k + 64 : k + 80);
      v = w1[row * MIN + col];
    }
    pAB_all[(size_t)y * 256 * KP + i] = f2b(v);
  } else if (i < 256 * KP + 512) {
    int jj = i - 256 * KP;
    int f = jj >> 6, jp = jj & 63;
    w1e2_all[y * 512 + jj] =
        __floats2half2_rn(w1[(2 * jp) * MIN + 160 + f], w1[(2 * jp + 1) * MIN + 160 + f]);
  } else if (i < 256 * KP + 512 + 256) {
    int jj = i - 256 * KP - 512;
    int o = jj >> 6, jp = jj & 63;
    w22_all[y * 256 + jj] = __floats2half2_rn(w2[o * WID + 2 * jp], w2[o * WID + 2 * jp + 1]);
  } else if (i < PACKN) {
    int jj = i - 256 * KP - 512 - 256;
    pj_all[y * 4096 + jj] = f2b(pj[jj]);
  }
}

// fused conversion of all gating weights to bf16
#define CW1 (GIN * GIN)   // 36864
#define CW2 (HH * GIN)    // 12288
__global__ void k_cvt6(const float* __restrict__ r_w1, const float* __restrict__ z_w1,
                       const float* __restrict__ c_w1, const float* __restrict__ r_w2,
                       const float* __restrict__ z_w2, const float* __restrict__ c_w2,
                       ushortT* __restrict__ rzw1, ushortT* __restrict__ cw1,
                       ushortT* __restrict__ rw2, ushortT* __restrict__ zw2,
                       ushortT* __restrict__ cw2) {
  int i = blockIdx.x * 256 + threadIdx.x;
  if (i < CW1) rzw1[i] = f2b(r_w1[i]);
  else if (i < 2 * CW1) rzw1[i] = f2b(z_w1[i - CW1]);
  else if (i < 3 * CW1) cw1[i - 2 * CW1] = f2b(c_w1[i - 2 * CW1]);
  else if (i < 3 * CW1 + CW2) rw2[i - 3 * CW1] = f2b(r_w2[i - 3 * CW1]);
  else if (i < 3 * CW1 + 2 * CW2) zw2[i - 3 * CW1 - CW2] = f2b(z_w2[i - 3 * CW1 - CW2]);
  else if (i < 3 * CW1 + 3 * CW2) cw2[i - 3 * CW1 - 2 * CW2] = f2b(c_w2[i - 3 * CW1 - 2 * CW2]);
}

// ---- initial LayerNorm: writes ncat0_{f,r} + hn copy into cAB rows (+256) ----
__global__ __launch_bounds__(256) void k_ln_init(
    const float* __restrict__ x, const float* __restrict__ xs,
    const float* __restrict__ lw, const float* __restrict__ lb,
    ushortT* __restrict__ ncf0, ushortT* __restrict__ ncr0,
    ushortT* __restrict__ ncf1, ushortT* __restrict__ ncr1,
    ushortT* __restrict__ cABf, ushortT* __restrict__ cABr) {
  int t = threadIdx.x;
  int node = blockIdx.x * 4 + (t >> 6), lane = t & 63;
  if (node >= NN) return;
  float v = x[(size_t)node * HH + lane];
  float mean = wave_sum64(v) * (1.0f / 64.0f);
  float d = v - mean;
  float var = wave_sum64(d * d) * (1.0f / 64.0f);
  ushortT val = f2b(d * rsqrtf(var + 1e-5f) * lw[lane] + lb[lane]);
  ncf0[(size_t)node * KP + lane] = val;
  ncr0[(size_t)node * KP + lane] = val;
  cABf[(size_t)node * CROW + 256 + lane] = val;
  cABr[(size_t)node * CROW + 256 + lane] = val;
  if (lane < SDIM) {
    ushortT xv = f2b(xs[(size_t)node * SDIM + lane]);
    ncf0[(size_t)node * KP + HH + lane] = xv;
    ncr0[(size_t)node * KP + HH + lane] = xv;
    ncf1[(size_t)node * KP + HH + lane] = xv;
    ncr1[(size_t)node * KP + HH + lane] = xv;
    ncf0[(size_t)node * KP + 80 + lane] = 0;
    ncr0[(size_t)node * KP + 80 + lane] = 0;
    ncf1[(size_t)node * KP + 80 + lane] = 0;
    ncr1[(size_t)node * KP + 80 + lane] = 0;
  }
}

// ---- node projection GEMM: y = dir | nchunk<<1 ; C rows stride CROW (f16 out) ----
__global__ __launch_bounds__(256) void k_proj2(
    const ushortT* __restrict__ Af, const ushortT* __restrict__ Ar,
    const ushortT* __restrict__ Wf, const ushortT* __restrict__ Wr,
    ushortT* __restrict__ Cf, ushortT* __restrict__ Cr) {
  int dir = blockIdx.y & 1;
  int n0 = (blockIdx.y >> 1) * 64;
  const ushortT* A = dir ? Ar : Af;
  const ushortT* W = dir ? Wr : Wf;
  ushortT* C = dir ? Cr : Cf;
  int w = threadIdx.x >> 6, l = threadIdx.x & 63;
  int m0 = blockIdx.x * 64 + w * 16;
  int rowa = m0 + (l & 15);
  int kb = l >> 4;
  bf16x8 afr0 = {0,0,0,0,0,0,0,0}, afr1 = afr0, afr2 = afr0;
  if (rowa < NN) {
    const ushortT* ap = A + (size_t)rowa * KP + kb * 8;
    afr0 = *(const bf16x8*)(ap);
    afr1 = *(const bf16x8*)(ap + 32);
    afr2 = *(const bf16x8*)(ap + 64);
  }
  int crow = m0 + (l >> 4) * 4;
  int ccol0 = l & 15;
  f32x4 acc[4];
#pragma unroll
  for (int n = 0; n < 4; ++n) acc[n] = (f32x4){0.f, 0.f, 0.f, 0.f};
  const ushortT* wbase = W + (size_t)(n0 + (l & 15)) * KP + kb * 8;
#pragma unroll
  for (int n = 0; n < 4; ++n) {
    const ushortT* wp = wbase + (size_t)(16 * n) * KP;
    acc[n] = __builtin_amdgcn_mfma_f32_16x16x32_bf16(afr0, *(const bf16x8*)(wp), acc[n], 0, 0, 0);
    acc[n] = __builtin_amdgcn_mfma_f32_16x16x32_bf16(afr1, *(const bf16x8*)(wp + 32), acc[n], 0, 0, 0);
    acc[n] = __builtin_amdgcn_mfma_f32_16x16x32_bf16(afr2, *(const bf16x8*)(wp + 64), acc[n], 0, 0, 0);
  }
#pragma unroll
  for (int n = 0; n < 4; ++n) {
    int col = n0 + ccol0 + n * 16;
#pragma unroll
    for (int r = 0; r < 4; ++r) {
      int row = crow + r;
      if (row < NN)
        C[(size_t)row * CROW + col] = __half_as_ushort(__float2half(acc[n][r]));
    }
  }
}

// ---- wave-granular MFMA GEMM: 64-thr blocks, grid (M/16, Nc/64) ----
template <int ACT, int BF16OUT, int KD>
__global__ __launch_bounds__(64) void k_gemm3(
    const ushortT* __restrict__ A, int lda, const ushortT* __restrict__ W,
    const float* __restrict__ bias, void* __restrict__ Cout, int ldc, int M,
    const float* __restrict__ zv, const float* __restrict__ xp) {
  constexpr int KS = KD / 32;
  int l = threadIdx.x;
  int m0 = blockIdx.x * 16;
  int n0 = blockIdx.y * 64;
  int rowa = m0 + (l & 15);
  int kb = l >> 4;
  bf16x8 afr[KS];
#pragma unroll
  for (int ks = 0; ks < KS; ++ks) {
    afr[ks] = (bf16x8){0, 0, 0, 0, 0, 0, 0, 0};
    if (rowa < M) afr[ks] = *(const bf16x8*)(A + (size_t)rowa * lda + ks * 32 + kb * 8);
  }
  f32x4 acc[4];
#pragma unroll
  for (int n = 0; n < 4; ++n) acc[n] = (f32x4){0.f, 0.f, 0.f, 0.f};
  const ushortT* wbase = W + (size_t)(n0 + (l & 15)) * KD + kb * 8;
#pragma unroll
  for (int n = 0; n < 4; ++n) {
    const ushortT* wp = wbase + (size_t)(16 * n) * KD;
#pragma unroll
    for (int ks = 0; ks < KS; ++ks)
      acc[n] = __builtin_amdgcn_mfma_f32_16x16x32_bf16(afr[ks], *(const bf16x8*)(wp + ks * 32),
                                                       acc[n], 0, 0, 0);
  }
  int crow = m0 + (l >> 4) * 4;
  int ccol0 = n0 + (l & 15);
#pragma unroll
  for (int n = 0; n < 4; ++n) {
    int col = ccol0 + n * 16;
    float bv = bias ? bias[col] : 0.f;
#pragma unroll
    for (int r = 0; r < 4; ++r) {
      int row = crow + r;
      if (row < M) {
        float v = acc[n][r] + bv;
        if (ACT == 1) v = fmaxf(v, 0.f);
        else if (ACT == 2) v = 1.f / (1.f + expf(-v));
        else if (ACT == 3) v = tanhf(v);
        else if (ACT == 5) {
          float z = zv[(size_t)row * HH + col];
          float xv = xp[(size_t)row * HH + col];
          v = (1.f - z) * xv + z * tanhf(v);
        }
        if (BF16OUT)
          ((ushortT*)Cout)[(size_t)row * ldc + col] = f2b(v);
        else
          ((float*)Cout)[(size_t)row * ldc + col] = v;
      }
    }
  }
}

// dual r2/z2 gemm (sigmoid), wave-granular: y=0 -> outR + gi[0:64]=r*x ; y=1 -> outZ
__global__ __launch_bounds__(64) void k_gemm_rz3(
    const ushortT* __restrict__ hid, const ushortT* __restrict__ rw2,
    const ushortT* __restrict__ zw2, const float* __restrict__ rb2,
    const float* __restrict__ zb2, float* __restrict__ outR, float* __restrict__ outZ,
    const float* __restrict__ x, ushortT* __restrict__ gi) {
  int y = blockIdx.y;
  const ushortT* A = hid + (y ? GIN : 0);
  const ushortT* W = y ? zw2 : rw2;
  const float* bias = y ? zb2 : rb2;
  float* C = y ? outZ : outR;
  constexpr int KS = GIN / 32;
  int l = threadIdx.x;
  int m0 = blockIdx.x * 16;
  int rowa = m0 + (l & 15);
  int kb = l >> 4;
  bf16x8 afr[KS];
#pragma unroll
  for (int ks = 0; ks < KS; ++ks) {
    afr[ks] = (bf16x8){0, 0, 0, 0, 0, 0, 0, 0};
    if (rowa < NN) afr[ks] = *(const bf16x8*)(A + (size_t)rowa * 384 + ks * 32 + kb * 8);
  }
  f32x4 acc[4];
#pragma unroll
  for (int n = 0; n < 4; ++n) acc[n] = (f32x4){0.f, 0.f, 0.f, 0.f};
  const ushortT* wbase = W + (size_t)(l & 15) * GIN + kb * 8;
#pragma unroll
  for (int n = 0; n < 4; ++n) {
    const ushortT* wp = wbase + (size_t)(16 * n) * GIN;
#pragma unroll
    for (int ks = 0; ks < KS; ++ks)
      acc[n] = __builtin_amdgcn_mfma_f32_16x16x32_bf16(afr[ks], *(const bf16x8*)(wp + ks * 32),
                                                       acc[n], 0, 0, 0);
  }
  int crow = m0 + (l >> 4) * 4;
  int ccol0 = l & 15;
#pragma unroll
  for (int n = 0; n < 4; ++n) {
    int col = ccol0 + n * 16;
    float bv = bias[col];
#pragma unroll
    for (int r = 0; r < 4; ++r) {
      int row = crow + r;
      if (row < NN) {
        float v = acc[n][r] + bv;
        float sig = 1.f / (1.f + expf(-v));
        C[(size_t)row * HH + col] = sig;
        if (y == 0)  // fused candin: gi[0:64] = r * x
          gi[(size_t)row * GIN + col] = f2b(sig * x[(size_t)row * HH + col]);
      }
    }
  }
}

// per-edge MLP: returns this lane's head-q score (after 4-lane reduce)
__device__ __forceinline__ float edge_mlp(
    const __half2* __restrict__ cAB2, int other, int owner, uint4 efraw,
    const __half2 (*w1e2_s)[64], const __half2 (*w22_s)[64], int q) {
  const __half2* cA2 = cAB2 + (size_t)other * (CROW / 2);
  const __half2* cB2 = cAB2 + (size_t)owner * (CROW / 2) + 64;
  U4H8 efu;
  efu.u = efraw;
  __half2 efb[8];
#pragma unroll
  for (int f2v = 0; f2v < 4; ++f2v) {
    efb[2 * f2v] = __half2half2(__low2half(efu.h[f2v]));
    efb[2 * f2v + 1] = __half2half2(__high2half(efu.h[f2v]));
  }
  float pf[4] = {0.f, 0.f, 0.f, 0.f};
#pragma unroll
  for (int c = 0; c < 4; ++c) {
    int jp0 = c * 16 + q * 4;
    U4H8 ua, ub;
    ua.u = *(const uint4*)(cA2 + jp0);
    ub.u = *(const uint4*)(cB2 + jp0);
    __half2 h2v[4];
#pragma unroll
    for (int i2 = 0; i2 < 4; ++i2) h2v[i2] = __hadd2(ua.h[i2], ub.h[i2]);
#pragma unroll
    for (int f = 0; f < 8; ++f) {
      U4H8 wv;
      wv.u = *(const uint4*)(&w1e2_s[f][jp0]);
#pragma unroll
      for (int i2 = 0; i2 < 4; ++i2) h2v[i2] = __hfma2(efb[f], wv.h[i2], h2v[i2]);
    }
#pragma unroll
    for (int i2 = 0; i2 < 4; ++i2) h2v[i2] = relu2(h2v[i2]);
#pragma unroll
    for (int o = 0; o < 4; ++o) {
      U4H8 wv;
      wv.u = *(const uint4*)(&w22_s[o][jp0]);
      __half2 p2 = __hmul2(h2v[0], wv.h[0]);
      p2 = __hfma2(h2v[1], wv.h[1], p2);
      p2 = __hfma2(h2v[2], wv.h[2], p2);
      p2 = __hfma2(h2v[3], wv.h[3], p2);
      pf[o] += __low2float(p2) + __high2float(p2);
    }
  }
#pragma unroll
  for (int m = 1; m <= 2; m <<= 1) {
    pf[0] += __shfl_xor(pf[0], m, 64);
    pf[1] += __shfl_xor(pf[1], m, 64);
    pf[2] += __shfl_xor(pf[2], m, 64);
    pf[3] += __shfl_xor(pf[3], m, 64);
  }
  return (q == 0) ? pf[0] : (q == 1) ? pf[1] : (q == 2) ? pf[2] : pf[3];
}

// ---- FUSED edge-MLP + softmax/sigmoid + aggregate (per-node wave) ----
// y=0: fwd (softmax, wout); y=1: rev (sigmoid -> outRW). agg written bf16.
// hn read from cAB row +256 (L1/L2-warm from the MLP pass).
__global__ __launch_bounds__(256) void k_edgeagg(
    const ushortT* __restrict__ cABf, const ushortT* __restrict__ cABr,
    const int4* __restrict__ pos_f, const int4* __restrict__ pos_r,
    const uint4* __restrict__ efh_f, const uint4* __restrict__ efh_r,
    const __half2* __restrict__ w1e2_f, const __half2* __restrict__ w1e2_r,
    const __half2* __restrict__ w22_f, const __half2* __restrict__ w22_r,
    const int* __restrict__ rp_d, const int* __restrict__ rp_s,
    float* __restrict__ s_seq, float* __restrict__ ws_seq,
    float* __restrict__ wout, float* __restrict__ outRW,
    ushortT* __restrict__ agg_f, ushortT* __restrict__ agg_r, int hop) {
  int y = blockIdx.y;
  const ushortT* cAB = y ? cABr : cABf;
  const __half2* cAB2 = (const __half2*)cAB;
  const int4* pos = y ? pos_r : pos_f;
  const uint4* efh = y ? efh_r : efh_f;
  const __half2* w1e2 = y ? w1e2_r : w1e2_f;
  const __half2* w22 = y ? w22_r : w22_f;
  const int* rp = y ? rp_s : rp_d;
  ushortT* agg = y ? agg_r : agg_f;
  __shared__ __half2 w1e2_s[8][64];
  __shared__ __half2 w22_s[4][64];
  __shared__ float w_s[4][64][4];
  __shared__ int ot_s[4][64];
  int t = threadIdx.x;
  for (int i = t; i < 512; i += 256) w1e2_s[i >> 6][i & 63] = w1e2[i];
  if (t < 256) w22_s[t >> 6][t & 63] = w22[t];
  __syncthreads();
  int wvi = t >> 6, lane = t & 63;
  int node = blockIdx.x * 4 + wvi;
  if (node >= NN) return;
  int beg = rp[node], end = rp[node + 1];
  int deg = end - beg;
  bool small = (deg <= 64);
  int li = lane >> 2, q = lane & 3;
  float mxv = 0.f, invv = 0.f;

  if (small) {
    float sv[4];
    int ee4[4];
#pragma unroll
    for (int u = 0; u < 4; ++u) { sv[u] = -1e30f; ee4[u] = 0; }
#pragma unroll
    for (int u = 0; u < 4; ++u) {
      if (u * 16 < deg) {  // wave-uniform guard
        int idx = beg + li + u * 16;
        bool val = idx < end;
        int idxc = val ? idx : beg;
        int4 pr = pos[idxc];
        ee4[u] = pr.x;
        if (q == 0 && val) ot_s[wvi][li + u * 16] = pr.y;
        float pv = edge_mlp(cAB2, pr.y, pr.z, efh[idxc], w1e2_s, w22_s, q);
        if (y) {
          float sig = 1.f / (1.f + expf(-pv));
          if (val) {
            outRW[(size_t)pr.x * (NHEAD * KHOP) + q * KHOP + hop] = sig;
            w_s[wvi][li + u * 16][q] = sig;
          }
        } else {
          sv[u] = val ? (pv > 0.f ? pv : 0.01f * pv) * 0.25f : -1e30f;
        }
      }
    }
    if (y == 0 && deg > 0) {
      float mx = fmaxf(fmaxf(sv[0], sv[1]), fmaxf(sv[2], sv[3]));
#pragma unroll
      for (int m = 4; m <= 32; m <<= 1) mx = fmaxf(mx, __shfl_xor(mx, m, 64));
      float ex[4];
      float sum = 0.f;
#pragma unroll
      for (int u = 0; u < 4; ++u) {
        ex[u] = (sv[u] > -1e29f) ? expf(sv[u] - mx) : 0.f;
        sum += ex[u];
      }
#pragma unroll
      for (int m = 4; m <= 32; m <<= 1) sum += __shfl_xor(sum, m, 64);
      float inv = 1.f / (sum + 1e-9f);
#pragma unroll
      for (int u = 0; u < 4; ++u) {
        if (beg + li + u * 16 < end) {
          float wv = ex[u] * inv;
          wout[(size_t)ee4[u] * (NHEAD * KHOP) + q * KHOP + hop] = wv;
          w_s[wvi][li + u * 16][q] = wv;
        }
      }
    }
  } else {
    // deg > 64 rare path: scores to s_seq/ws_seq, then classic multi-pass
    for (int ii = beg + li; ii < end; ii += 16) {
      int4 pr = pos[ii];
      float pv = edge_mlp(cAB2, pr.y, pr.z, efh[ii], w1e2_s, w22_s, q);
      if (y) {
        float sig = 1.f / (1.f + expf(-pv));
        outRW[(size_t)pr.x * (NHEAD * KHOP) + q * KHOP + hop] = sig;
        ws_seq[(size_t)ii * 4 + q] = sig;
      } else {
        s_seq[(size_t)ii * 4 + q] = (pv > 0.f ? pv : 0.01f * pv) * 0.25f;
      }
    }
    if (y == 0) {
      float mx = -1e30f;
      for (int ii = beg + li; ii < end; ii += 16)
        mx = fmaxf(mx, s_seq[(size_t)ii * 4 + q]);
#pragma unroll
      for (int m = 4; m <= 32; m <<= 1) mx = fmaxf(mx, __shfl_xor(mx, m, 64));
      float sum = 0.f;
      for (int ii = beg + li; ii < end; ii += 16)
        sum += expf(s_seq[(size_t)ii * 4 + q] - mx);
#pragma unroll
      for (int m = 4; m <= 32; m <<= 1) sum += __shfl_xor(sum, m, 64);
      float inv = 1.f / (sum + 1e-9f);
      for (int ii = beg + li; ii < end; ii += 16) {
        wout[(size_t)pos[ii].x * (NHEAD * KHOP) + q * KHOP + hop] =
            expf(s_seq[(size_t)ii * 4 + q] - mx) * inv;
      }
      mxv = mx;
      invv = inv;
    }
  }
  // aggregate (lane = column); hn at cAB row +256 (L2-warm)
  int hd = lane >> 4;
  float acc = 0.f;
  if (small) {
    for (int ii = 0; ii < deg; ii += 8) {
#pragma unroll
      for (int u = 0; u < 8; ++u) {
        int ed = ii + u;
        int edc = (ed < deg) ? ed : 0;
        size_t ot = (size_t)ot_s[wvi][edc] * CROW + 256;
        float w = w_s[wvi][edc][hd];
        float hv = b2f(cAB[ot + lane]);
        acc += ((ed < deg) ? w : 0.f) * hv;
      }
    }
  } else {
    float mx_hd = 0.f, inv_hd = 0.f;
    if (y == 0) {
      mx_hd = __shfl(mxv, hd, 64);
      inv_hd = __shfl(invv, hd, 64);
    }
    for (int ii = beg; ii < end; ++ii) {
      int4 pr = pos[ii];
      float w;
      if (y == 0)
        w = expf(s_seq[(size_t)ii * 4 + hd] - mx_hd) * inv_hd;
      else
        w = ws_seq[(size_t)ii * 4 + hd];
      acc += w * b2f(cAB[(size_t)pr.y * CROW + 256 + lane]);
    }
  }
  agg[(size_t)node * HH + lane] = f2b(acc);
}

// ---- proj(agg) + residual + LN/gate epilogue (MFMA, wave-granular, both dirs) ----
// DO_LN also writes the hn copy into the NEXT hop's cAB rows (+256).
template <int DO_LN, int DO_GATE>
__global__ __launch_bounds__(64) void k_projout(
    const ushortT* __restrict__ agg_f, const ushortT* __restrict__ agg_r,
    const ushortT* __restrict__ pj_f, const ushortT* __restrict__ pj_r,
    float* __restrict__ h_f, float* __restrict__ h_r,
    ushortT* __restrict__ ncf_n, ushortT* __restrict__ ncr_n,
    ushortT* __restrict__ cABf, ushortT* __restrict__ cABr,
    const float* __restrict__ lnw, const float* __restrict__ lnb,
    const float* __restrict__ x, ushortT* __restrict__ gi) {
  int y = blockIdx.y;
  const ushortT* A = y ? agg_r : agg_f;
  const ushortT* W = y ? pj_r : pj_f;
  float* h = y ? h_r : h_f;
  ushortT* ncat_n = y ? ncr_n : ncf_n;
  ushortT* cab = y ? cABr : cABf;
  int l = threadIdx.x;
  int m0 = blockIdx.x * 16;
  int rowa = m0 + (l & 15);
  int kb = l >> 4;
  bf16x8 afr0 = {0, 0, 0, 0, 0, 0, 0, 0}, afr1 = afr0;
  if (rowa < NN) {
    afr0 = *(const bf16x8*)(A + (size_t)rowa * HH + kb * 8);
    afr1 = *(const bf16x8*)(A + (size_t)rowa * HH + 32 + kb * 8);
  }
  f32x4 acc[4];
#pragma unroll
  for (int n = 0; n < 4; ++n) acc[n] = (f32x4){0.f, 0.f, 0.f, 0.f};
  const ushortT* wbase = W + (size_t)(l & 15) * HH + kb * 8;
#pragma unroll
  for (int n = 0; n < 4; ++n) {
    const ushortT* wp = wbase + (size_t)(16 * n) * HH;
    acc[n] = __builtin_amdgcn_mfma_f32_16x16x32_bf16(afr0, *(const bf16x8*)(wp), acc[n], 0, 0, 0);
    acc[n] = __builtin_amdgcn_mfma_f32_16x16x32_bf16(afr1, *(const bf16x8*)(wp + 32), acc[n], 0, 0, 0);
  }
  int crow = m0 + (l >> 4) * 4;
  int ccol0 = l & 15;
#pragma unroll
  for (int r = 0; r < 4; ++r) {
    int row = crow + r;
    if (row >= NN) continue;
    float hv[4];
#pragma unroll
    for (int n = 0; n < 4; ++n)
      hv[n] = h[(size_t)row * HH + ccol0 + n * 16] + acc[n][r];
    float s = hv[0] + hv[1] + hv[2] + hv[3];
#pragma unroll
    for (int m = 1; m <= 8; m <<= 1) s += __shfl_xor(s, m, 64);
    float mean = s * (1.0f / 64.0f);
    float ss = 0.f;
#pragma unroll
    for (int n = 0; n < 4; ++n) {
      float d = hv[n] - mean;
      ss += d * d;
    }
#pragma unroll
    for (int m = 1; m <= 8; m <<= 1) ss += __shfl_xor(ss, m, 64);
    float rstd = rsqrtf(ss * (1.0f / 64.0f) + 1e-5f);
#pragma unroll
    for (int n = 0; n < 4; ++n) {
      int col = ccol0 + n * 16;
      size_t g = (size_t)row * HH + col;
      h[g] = hv[n];
      if (DO_LN) {
        ushortT val = f2b((hv[n] - mean) * rstd * lnw[col] + lnb[col]);
        ncat_n[(size_t)row * KP + col] = val;
        cab[(size_t)row * CROW + 256 + col] = val;
      }
      if (DO_GATE) {
        float xv = x[g];
        if (y == 0) {
          gi[(size_t)row * GIN + col] = f2b(xv);
          gi[(size_t)row * GIN + 64 + col] = f2b(hv[n] - xv);
        } else {
          gi[(size_t)row * GIN + 128 + col] = f2b(hv[n] - xv);
        }
      }
    }
  }
}

extern "C" void kernel_launch(void* const* d_in, const int* in_sizes, int n_in,
                              void* d_out, int out_size, void* d_ws, size_t ws_size,
                              hipStream_t stream) {
  const float* x = (const float*)d_in[0];
  const float* xs = (const float*)d_in[1];
  const int* ei = (const int*)d_in[2];
  const float* ef = (const float*)d_in[3];
  const float* fw1 = (const float*)d_in[4];
  const float* fw2 = (const float*)d_in[5];
  const float* fpj = (const float*)d_in[6];
  const float* rw1 = (const float*)d_in[7];
  const float* rw2 = (const float*)d_in[8];
  const float* rpj = (const float*)d_in[9];
  const float* lnw = (const float*)d_in[10];
  const float* lnb = (const float*)d_in[11];
  const float* r_w1 = (const float*)d_in[12];
  const float* r_b1 = (const float*)d_in[13];
  const float* r_w2 = (const float*)d_in[14];
  const float* r_b2 = (const float*)d_in[15];
  const float* z_w1 = (const float*)d_in[16];
  const float* z_b1 = (const float*)d_in[17];
  const float* z_w2 = (const float*)d_in[18];
  const float* z_b2 = (const float*)d_in[19];
  const float* c_w1 = (const float*)d_in[20];
  const float* c_b1 = (const float*)d_in[21];
  const float* c_w2 = (const float*)d_in[22];
  const float* c_b2 = (const float*)d_in[23];
  const int* srcp = ei;
  const int* dstp = ei + EE;

  float* outF = (float*)d_out;
  float* outFW = outF + (size_t)NN * HH;
  float* outRW = outFW + (size_t)EE * NHEAD * KHOP;
  float* outZ = outRW + (size_t)EE * NHEAD * KHOP;
  float* outR = outZ + (size_t)NN * HH;

  char* Wb = (char*)d_ws;
  size_t off = 0;
  auto alloc = [&](size_t bytes) -> void* {
    void* p = Wb + off;
    off += (bytes + 255) & ~(size_t)255;
    return p;
  };
  float* h_fwd = (float*)alloc((size_t)NN * HH * 4);
  float* h_rev = (float*)alloc((size_t)NN * HH * 4);
  ushortT* ncat_f0 = (ushortT*)alloc((size_t)NN * KP * 2);
  ushortT* ncat_r0 = (ushortT*)alloc((size_t)NN * KP * 2);
  ushortT* ncat_f1 = (ushortT*)alloc((size_t)NN * KP * 2);
  ushortT* ncat_r1 = (ushortT*)alloc((size_t)NN * KP * 2);
  float* s_seq = (float*)alloc((size_t)EE * NHEAD * 4);
  float* ws_seq = (float*)alloc((size_t)EE * NHEAD * 4);
  // big region: hops -> cAB_f/r (stride CROW, 16MB each); gating -> hid_bf (19.2MB)
  char* big = (char*)alloc((size_t)2 * NN * CROW * 2);
  ushortT* cAB_f = (ushortT*)big;
  ushortT* cAB_r = (ushortT*)(big + (size_t)NN * CROW * 2);
  ushortT* hid_bf = (ushortT*)big;
  ushortT* gi_bf = (ushortT*)alloc((size_t)NN * GIN * 2);
  ushortT* agg_f = (ushortT*)alloc((size_t)NN * HH * 2);
  ushortT* agg_r = (ushortT*)alloc((size_t)NN * HH * 2);
  ushortT* packAB_bf = (ushortT*)alloc((size_t)4 * 256 * KP * 2);
  __half2* w1e2h = (__half2*)alloc((size_t)4 * 512 * 4);
  __half2* w22h = (__half2*)alloc((size_t)4 * 256 * 4);
  ushortT* pj_bf = (ushortT*)alloc((size_t)4 * 4096 * 2);
  ushortT* rzw1_bf = (ushortT*)alloc((size_t)384 * GIN * 2);
  ushortT* rw2_bf = (ushortT*)alloc((size_t)HH * GIN * 2);
  ushortT* zw2_bf = (ushortT*)alloc((size_t)HH * GIN * 2);
  ushortT* cw1_bf = (ushortT*)alloc((size_t)GIN * GIN * 2);
  ushortT* cw2_bf = (ushortT*)alloc((size_t)HH * GIN * 2);
  float* rz_b1 = (float*)alloc(384 * 4);
  int* rp_d = (int*)alloc((NN + 8) * 4);
  int* rp_s = (int*)alloc((NN + 8) * 4);
  int* cur2 = (int*)alloc((size_t)2 * NN * 4);
  int* cur_d = cur2;
  int* cur_s = cur2 + NN;
  int* eid_d = (int*)alloc((size_t)EE * 4);
  int* eid_s = (int*)alloc((size_t)EE * 4);
  int4* pos_f = (int4*)alloc((size_t)EE * 16);
  int4* pos_r = (int4*)alloc((size_t)EE * 16);
  uint4* efh_f = (uint4*)alloc((size_t)EE * 16);
  uint4* efh_r = (uint4*)alloc((size_t)EE * 16);

  (void)hipMemcpyAsync(h_fwd, x, (size_t)NN * HH * 4, hipMemcpyDeviceToDevice, stream);
  (void)hipMemcpyAsync(h_rev, x, (size_t)NN * HH * 4, hipMemcpyDeviceToDevice, stream);
  (void)hipMemcpyAsync(rz_b1, r_b1, GIN * 4, hipMemcpyDeviceToDevice, stream);
  (void)hipMemcpyAsync(rz_b1 + GIN, z_b1, GIN * 4, hipMemcpyDeviceToDevice, stream);

  const int EB = (EE + 255) / 256, NW = (NN + 3) / 4;
  const int PB = (PACKN + 255) / 256;

  // weight repacks
  dim3 gPack(PB, 4);
  k_pack_bf<<<gPack, 256, 0, stream>>>(fw1, rw1, fw2, rw2, fpj, rpj, packAB_bf,
                                       w1e2h, w22h, pj_bf);
  k_cvt6<<<(3 * CW1 + 3 * CW2 + 255) / 256, 256, 0, stream>>>(
      r_w1, z_w1, c_w1, r_w2, z_w2, c_w2, rzw1_bf, cw1_bf, rw2_bf, zw2_bf, cw2_bf);

  // CSR build (both directions)
  (void)hipMemsetAsync(cur2, 0, (size_t)2 * NN * 4, stream);
  k_histo2<<<EB, 256, 0, stream>>>(srcp, dstp, cur_s, cur_d);
  k_scan2<<<2, 1024, 0, stream>>>(cur_d, cur_s, rp_d, rp_s);
  (void)hipMemsetAsync(cur2, 0, (size_t)2 * NN * 4, stream);
  k_scatter2<<<EB, 256, 0, stream>>>(srcp, dstp, rp_s, rp_d, cur_s, cur_d, eid_s, eid_d);
  k_sortseg2<<<(2 * NN + 3) / 4, 256, 0, stream>>>(rp_d, rp_s, eid_d, eid_s);
  k_mkpos2<<<EB, 256, 0, stream>>>(eid_d, eid_s, srcp, dstp, ef, pos_f, pos_r, efh_f, efh_r);

  // initial LN (h = x for both chains) + hn copy into cAB rows
  k_ln_init<<<NW, 256, 0, stream>>>(x, xs, lnw, lnb, ncat_f0, ncat_r0, ncat_f1,
                                    ncat_r1, cAB_f, cAB_r);

  const int MB64 = (NN + 63) / 64;   // 391
  const int MB16 = (NN + 15) / 16;   // 1563
  dim3 gProj(MB64, 8), gEA(NW, 2), gPO(MB16, 2);
  for (int k = 0; k < KHOP; ++k) {
    const ushortT* nf = k ? ncat_f1 : ncat_f0;
    const ushortT* nr = k ? ncat_r1 : ncat_r0;
    k_proj2<<<gProj, 256, 0, stream>>>(nf, nr,
                                       packAB_bf + (size_t)k * 256 * KP,
                                       packAB_bf + (size_t)(2 + k) * 256 * KP,
                                       cAB_f, cAB_r);
    k_edgeagg<<<gEA, 256, 0, stream>>>(cAB_f, cAB_r, pos_f, pos_r, efh_f, efh_r,
                                       w1e2h + (size_t)k * 512,
                                       w1e2h + (size_t)(2 + k) * 512,
                                       w22h + (size_t)k * 256,
                                       w22h + (size_t)(2 + k) * 256,
                                       rp_d, rp_s, s_seq, ws_seq, outFW, outRW,
                                       agg_f, agg_r, k);
    if (k == 0)
      k_projout<1, 0><<<gPO, 64, 0, stream>>>(
          agg_f, agg_r, pj_bf + (size_t)k * 4096, pj_bf + (size_t)(2 + k) * 4096,
          h_fwd, h_rev, ncat_f1, ncat_r1, cAB_f, cAB_r, lnw, lnb, x, gi_bf);
    else
      k_projout<0, 1><<<gPO, 64, 0, stream>>>(
          agg_f, agg_r, pj_bf + (size_t)k * 4096, pj_bf + (size_t)(2 + k) * 4096,
          h_fwd, h_rev, ncat_f1, ncat_r1, cAB_f, cAB_r, lnw, lnb, x, gi_bf);
  }

  // gating (wave-granular grids for occupancy)
  dim3 gRZ1(MB16, 6), gRZ2(MB16, 2), gC1(MB16, 3), gF(MB16, 1);
  k_gemm3<1, 1, GIN><<<gRZ1, 64, 0, stream>>>(gi_bf, GIN, rzw1_bf, rz_b1, hid_bf,
                                              384, NN, nullptr, nullptr);
  k_gemm_rz3<<<gRZ2, 64, 0, stream>>>(hid_bf, rw2_bf, zw2_bf, r_b2, z_b2, outR, outZ,
                                      x, gi_bf);
  k_gemm3<1, 1, GIN><<<gC1, 64, 0, stream>>>(gi_bf, GIN, cw1_bf, c_b1, hid_bf, GIN,
                                             NN, nullptr, nullptr);
  k_gemm3<5, 0, GIN><<<gF, 64, 0, stream>>>(hid_bf, GIN, cw2_bf, c_b2, outF, HH, NN,
                                            outZ, x);
}

// Round 17
// 498.515 us; speedup vs baseline: 1.5605x; 1.5605x over previous
//
#include <hip/hip_runtime.h>
#include <hip/hip_fp16.h>
#include <math.h>

#define NN 25000
#define EE 400000
#define HH 64
#define NHEAD 4
#define SDIM 16
#define EFDIM 8
#define KHOP 2
#define MIN 168   // 2H + 2S + EF
#define WID 128
#define GIN 192
#define KP 96     // padded K for node-proj GEMM (80 -> 96)

typedef __attribute__((ext_vector_type(8))) short bf16x8;
typedef __attribute__((ext_vector_type(4))) float f32x4;
typedef unsigned short ushortT;
typedef unsigned int uintT;

__device__ __forceinline__ float wave_sum64(float v) {
#pragma unroll
  for (int m = 1; m <= 32; m <<= 1) v += __shfl_xor(v, m, 64);
  return v;
}

__device__ __forceinline__ ushortT f2b(float f) {
  uintT u = __float_as_uint(f);
  return (ushortT)((u + 0x7FFFu + ((u >> 16) & 1u)) >> 16);
}
__device__ __forceinline__ float b2f(ushortT h) {
  return __uint_as_float(((uintT)h) << 16);
}

union U4H8 {
  uint4 u;
  __half2 h[4];
};

// packed-f16 ReLU via sign-bit mask (no __hmax2 on ROCm 7.2)
__device__ __forceinline__ __half2 relu2(__half2 v) {
  union { __half2 h; uintT u; } x;
  x.h = v;
  uintT mask = ((x.u & 0x80008000u) >> 15) * 0xFFFFu;
  x.u &= ~mask;
  return x.h;
}

// ---------------- CSR build (both directions in one pass) ----------------
__global__ void k_histo2(const int* __restrict__ src, const int* __restrict__ dst,
                         int* __restrict__ cnt_s, int* __restrict__ cnt_d) {
  int e = blockIdx.x * 256 + threadIdx.x;
  if (e < EE) {
    atomicAdd(&cnt_d[dst[e]], 1);
    atomicAdd(&cnt_s[src[e]], 1);
  }
}

__global__ void k_scan2(const int* __restrict__ cnt_d, const int* __restrict__ cnt_s,
                        int* __restrict__ rp_d, int* __restrict__ rp_s) {
  const int* cnt = blockIdx.x ? cnt_s : cnt_d;
  int* rp = blockIdx.x ? rp_s : rp_d;
  __shared__ int part[1024];
  int t = threadIdx.x;
  const int CH = (NN + 1023) / 1024;
  int base = t * CH;
  int s = 0;
  for (int i = 0; i < CH; ++i) {
    int j = base + i;
    if (j < NN) s += cnt[j];
  }
  part[t] = s;
  __syncthreads();
  for (int off = 1; off < 1024; off <<= 1) {
    int v = (t >= off) ? part[t - off] : 0;
    __syncthreads();
    part[t] += v;
    __syncthreads();
  }
  int run = (t == 0) ? 0 : part[t - 1];
  for (int i = 0; i < CH; ++i) {
    int j = base + i;
    if (j < NN) { rp[j] = run; run += cnt[j]; }
  }
  if (t == 1023) rp[NN] = run;
}

__global__ void k_scatter2(const int* __restrict__ src, const int* __restrict__ dst,
                           const int* __restrict__ rp_s, const int* __restrict__ rp_d,
                           int* __restrict__ cur_s, int* __restrict__ cur_d,
                           int* __restrict__ eid_s, int* __restrict__ eid_d) {
  int e = blockIdx.x * 256 + threadIdx.x;
  if (e < EE) {
    int nd = dst[e];
    int pd = atomicAdd(&cur_d[nd], 1);
    eid_d[rp_d[nd] + pd] = e;
    int ns = src[e];
    int ps = atomicAdd(&cur_s[ns], 1);
    eid_s[rp_s[ns] + ps] = e;
  }
}

// wave-parallel bitonic sort of each segment (deterministic ascending order)
__global__ __launch_bounds__(256) void k_sortseg2(const int* __restrict__ rp_d,
                                                  const int* __restrict__ rp_s,
                                                  int* __restrict__ eid_d,
                                                  int* __restrict__ eid_s) {
  int gw = blockIdx.x * 4 + (threadIdx.x >> 6);
  int lane = threadIdx.x & 63;
  if (gw >= 2 * NN) return;
  const int* rp = (gw < NN) ? rp_d : rp_s;
  int* eids = (gw < NN) ? eid_d : eid_s;
  int node = (gw < NN) ? gw : gw - NN;
  int beg = rp[node], end = rp[node + 1];
  int deg = end - beg;
  if (deg <= 1) return;
  if (deg <= 64) {
    int v = (lane < deg) ? eids[beg + lane] : 0x7fffffff;
#pragma unroll
    for (int k = 2; k <= 64; k <<= 1) {
#pragma unroll
      for (int j = k >> 1; j > 0; j >>= 1) {
        int other = __shfl_xor(v, j, 64);
        bool takeMin = (((lane & k) == 0) == ((lane & j) == 0));
        v = takeMin ? min(v, other) : max(v, other);
      }
    }
    if (lane < deg) eids[beg + lane] = v;
  } else if (lane == 0) {
    for (int i = beg + 1; i < end; ++i) {
      int v = eids[i];
      int j = i - 1;
      while (j >= beg && eids[j] > v) { eids[j + 1] = eids[j]; --j; }
      eids[j + 1] = v;
    }
  }
}

// pos[ii] = {e, other_node, owner_node, 0}; position-ordered ef packed f16 (uint4)
__global__ void k_mkpos2(const int* __restrict__ eid_d, const int* __restrict__ eid_s,
                         const int* __restrict__ src, const int* __restrict__ dst,
                         const float* __restrict__ ef, int4* __restrict__ pos_f,
                         int4* __restrict__ pos_r, uint4* __restrict__ efh_f,
                         uint4* __restrict__ efh_r) {
  int i = blockIdx.x * 256 + threadIdx.x;
  if (i >= EE) return;
  int e1 = eid_d[i];
  pos_f[i] = make_int4(e1, src[e1], dst[e1], 0);
  int e2 = eid_s[i];
  pos_r[i] = make_int4(e2, dst[e2], src[e2], 0);
  {
    float4 a0 = *(const float4*)(ef + (size_t)e1 * EFDIM);
    float4 a1 = *(const float4*)(ef + (size_t)e1 * EFDIM + 4);
    U4H8 u;
    u.h[0] = __floats2half2_rn(a0.x, a0.y);
    u.h[1] = __floats2half2_rn(a0.z, a0.w);
    u.h[2] = __floats2half2_rn(a1.x, a1.y);
    u.h[3] = __floats2half2_rn(a1.z, a1.w);
    efh_f[i] = u.u;
  }
  {
    float4 b0 = *(const float4*)(ef + (size_t)e2 * EFDIM);
    float4 b1 = *(const float4*)(ef + (size_t)e2 * EFDIM + 4);
    U4H8 u;
    u.h[0] = __floats2half2_rn(b0.x, b0.y);
    u.h[1] = __floats2half2_rn(b0.z, b0.w);
    u.h[2] = __floats2half2_rn(b1.x, b1.y);
    u.h[3] = __floats2half2_rn(b1.z, b1.w);
    efh_r[i] = u.u;
  }
}

// weight repack: pAB bf16[256][96] + w1e2 half2[8][64] + w22 half2[4][64] + proj bf16[64][64]
#define PACKN (256 * KP + 512 + 256 + 4096)
__global__ void k_pack_bf(const float* __restrict__ fw1, const float* __restrict__ rw1,
                          const float* __restrict__ fw2, const float* __restrict__ rw2,
                          const float* __restrict__ fpj, const float* __restrict__ rpj,
                          ushortT* __restrict__ pAB_all, __half2* __restrict__ w1e2_all,
                          __half2* __restrict__ w22_all, ushortT* __restrict__ pj_all) {
  int y = blockIdx.y;
  const float* w1 = (y < 2) ? fw1 + (size_t)y * WID * MIN
                            : rw1 + (size_t)(y - 2) * WID * MIN;
  const float* w2 = (y < 2) ? fw2 + (size_t)y * NHEAD * WID
                            : rw2 + (size_t)(y - 2) * NHEAD * WID;
  const float* pj = (y < 2) ? fpj + (size_t)y * HH * HH
                            : rpj + (size_t)(y - 2) * HH * HH;
  int i = blockIdx.x * 256 + threadIdx.x;
  if (i < 256 * KP) {
    int j = i / KP, k = i % KP;
    float v = 0.f;
    if (k < 80) {
      int row = (j < 128) ? j : j - 128;
      int col = (j < 128) ? (k < 64 ? k : k + 64) : (k < 64 ? k + 64 : k + 80);
      v = w1[row * MIN + col];
    }
    pAB_all[(size_t)y * 256 * KP + i] = f2b(v);
  } else if (i < 256 * KP + 512) {
    int jj = i - 256 * KP;
    int f = jj >> 6, jp = jj & 63;
    w1e2_all[y * 512 + jj] =
        __floats2half2_rn(w1[(2 * jp) * MIN + 160 + f], w1[(2 * jp + 1) * MIN + 160 + f]);
  } else if (i < 256 * KP + 512 + 256) {
    int jj = i - 256 * KP - 512;
    int o = jj >> 6, jp = jj & 63;
    w22_all[y * 256 + jj] = __floats2half2_rn(w2[o * WID + 2 * jp], w2[o * WID + 2 * jp + 1]);
  } else if (i < PACKN) {
    int jj = i - 256 * KP - 512 - 256;
    pj_all[y * 4096 + jj] = f2b(pj[jj]);
  }
}

// fused conversion of all gating weights to bf16
#define CW1 (GIN * GIN)   // 36864
#define CW2 (HH * GIN)    // 12288
__global__ void k_cvt6(const float* __restrict__ r_w1, const float* __restrict__ z_w1,
                       const float* __restrict__ c_w1, const float* __restrict__ r_w2,
                       const float* __restrict__ z_w2, const float* __restrict__ c_w2,
                       ushortT* __restrict__ rzw1, ushortT* __restrict__ cw1,
                       ushortT* __restrict__ rw2, ushortT* __restrict__ zw2,
                       ushortT* __restrict__ cw2) {
  int i = blockIdx.x * 256 + threadIdx.x;
  if (i < CW1) rzw1[i] = f2b(r_w1[i]);
  else if (i < 2 * CW1) rzw1[i] = f2b(z_w1[i - CW1]);
  else if (i < 3 * CW1) cw1[i - 2 * CW1] = f2b(c_w1[i - 2 * CW1]);
  else if (i < 3 * CW1 + CW2) rw2[i - 3 * CW1] = f2b(r_w2[i - 3 * CW1]);
  else if (i < 3 * CW1 + 2 * CW2) zw2[i - 3 * CW1 - CW2] = f2b(z_w2[i - 3 * CW1 - CW2]);
  else if (i < 3 * CW1 + 3 * CW2) cw2[i - 3 * CW1 - 2 * CW2] = f2b(c_w2[i - 3 * CW1 - 2 * CW2]);
}

// ---- initial LayerNorm (h = x for both dirs): writes ncat0_{f,r}; xs/pad into all 4 ----
__global__ __launch_bounds__(256) void k_ln_init(
    const float* __restrict__ x, const float* __restrict__ xs,
    const float* __restrict__ lw, const float* __restrict__ lb,
    ushortT* __restrict__ ncf0, ushortT* __restrict__ ncr0,
    ushortT* __restrict__ ncf1, ushortT* __restrict__ ncr1) {
  int t = threadIdx.x;
  int node = blockIdx.x * 4 + (t >> 6), lane = t & 63;
  if (node >= NN) return;
  float v = x[(size_t)node * HH + lane];
  float mean = wave_sum64(v) * (1.0f / 64.0f);
  float d = v - mean;
  float var = wave_sum64(d * d) * (1.0f / 64.0f);
  ushortT val = f2b(d * rsqrtf(var + 1e-5f) * lw[lane] + lb[lane]);
  ncf0[(size_t)node * KP + lane] = val;
  ncr0[(size_t)node * KP + lane] = val;
  if (lane < SDIM) {
    ushortT xv = f2b(xs[(size_t)node * SDIM + lane]);
    ncf0[(size_t)node * KP + HH + lane] = xv;
    ncr0[(size_t)node * KP + HH + lane] = xv;
    ncf1[(size_t)node * KP + HH + lane] = xv;
    ncr1[(size_t)node * KP + HH + lane] = xv;
    ncf0[(size_t)node * KP + 80 + lane] = 0;
    ncr0[(size_t)node * KP + 80 + lane] = 0;
    ncf1[(size_t)node * KP + 80 + lane] = 0;
    ncr1[(size_t)node * KP + 80 + lane] = 0;
  }
}

// ---- node projection GEMM: y = dir | nchunk<<1 ; C = A[NN,96] @ W[256,96]^T (f16) ----
__global__ __launch_bounds__(256) void k_proj2(
    const ushortT* __restrict__ Af, const ushortT* __restrict__ Ar,
    const ushortT* __restrict__ Wf, const ushortT* __restrict__ Wr,
    ushortT* __restrict__ Cf, ushortT* __restrict__ Cr) {
  int dir = blockIdx.y & 1;
  int n0 = (blockIdx.y >> 1) * 64;
  const ushortT* A = dir ? Ar : Af;
  const ushortT* W = dir ? Wr : Wf;
  ushortT* C = dir ? Cr : Cf;
  int w = threadIdx.x >> 6, l = threadIdx.x & 63;
  int m0 = blockIdx.x * 64 + w * 16;
  int rowa = m0 + (l & 15);
  int kb = l >> 4;
  bf16x8 afr0 = {0,0,0,0,0,0,0,0}, afr1 = afr0, afr2 = afr0;
  if (rowa < NN) {
    const ushortT* ap = A + (size_t)rowa * KP + kb * 8;
    afr0 = *(const bf16x8*)(ap);
    afr1 = *(const bf16x8*)(ap + 32);
    afr2 = *(const bf16x8*)(ap + 64);
  }
  int crow = m0 + (l >> 4) * 4;
  int ccol0 = l & 15;
  f32x4 acc[4];
#pragma unroll
  for (int n = 0; n < 4; ++n) acc[n] = (f32x4){0.f, 0.f, 0.f, 0.f};
  const ushortT* wbase = W + (size_t)(n0 + (l & 15)) * KP + kb * 8;
#pragma unroll
  for (int n = 0; n < 4; ++n) {
    const ushortT* wp = wbase + (size_t)(16 * n) * KP;
    acc[n] = __builtin_amdgcn_mfma_f32_16x16x32_bf16(afr0, *(const bf16x8*)(wp), acc[n], 0, 0, 0);
    acc[n] = __builtin_amdgcn_mfma_f32_16x16x32_bf16(afr1, *(const bf16x8*)(wp + 32), acc[n], 0, 0, 0);
    acc[n] = __builtin_amdgcn_mfma_f32_16x16x32_bf16(afr2, *(const bf16x8*)(wp + 64), acc[n], 0, 0, 0);
  }
#pragma unroll
  for (int n = 0; n < 4; ++n) {
    int col = n0 + ccol0 + n * 16;
#pragma unroll
    for (int r = 0; r < 4; ++r) {
      int row = crow + r;
      if (row < NN)
        C[(size_t)row * 256 + col] = __half_as_ushort(__float2half(acc[n][r]));
    }
  }
}

// ---- wave-granular MFMA GEMM: 64-thr blocks, grid (M/16, Nc/64) ----
// ACT 5 = fused GRU final: out=(1-z)x+z*tanh(v)
template <int ACT, int BF16OUT, int KD>
__global__ __launch_bounds__(64) void k_gemm3(
    const ushortT* __restrict__ A, int lda, const ushortT* __restrict__ W,
    const float* __restrict__ bias, void* __restrict__ Cout, int ldc, int M,
    const float* __restrict__ zv, const float* __restrict__ xp) {
  constexpr int KS = KD / 32;
  int l = threadIdx.x;
  int m0 = blockIdx.x * 16;
  int n0 = blockIdx.y * 64;
  int rowa = m0 + (l & 15);
  int kb = l >> 4;
  bf16x8 afr[KS];
#pragma unroll
  for (int ks = 0; ks < KS; ++ks) {
    afr[ks] = (bf16x8){0, 0, 0, 0, 0, 0, 0, 0};
    if (rowa < M) afr[ks] = *(const bf16x8*)(A + (size_t)rowa * lda + ks * 32 + kb * 8);
  }
  f32x4 acc[4];
#pragma unroll
  for (int n = 0; n < 4; ++n) acc[n] = (f32x4){0.f, 0.f, 0.f, 0.f};
  const ushortT* wbase = W + (size_t)(n0 + (l & 15)) * KD + kb * 8;
#pragma unroll
  for (int n = 0; n < 4; ++n) {
    const ushortT* wp = wbase + (size_t)(16 * n) * KD;
#pragma unroll
    for (int ks = 0; ks < KS; ++ks)
      acc[n] = __builtin_amdgcn_mfma_f32_16x16x32_bf16(afr[ks], *(const bf16x8*)(wp + ks * 32),
                                                       acc[n], 0, 0, 0);
  }
  int crow = m0 + (l >> 4) * 4;
  int ccol0 = n0 + (l & 15);
#pragma unroll
  for (int n = 0; n < 4; ++n) {
    int col = ccol0 + n * 16;
    float bv = bias ? bias[col] : 0.f;
#pragma unroll
    for (int r = 0; r < 4; ++r) {
      int row = crow + r;
      if (row < M) {
        float v = acc[n][r] + bv;
        if (ACT == 1) v = fmaxf(v, 0.f);
        else if (ACT == 2) v = 1.f / (1.f + expf(-v));
        else if (ACT == 3) v = tanhf(v);
        else if (ACT == 5) {
          float z = zv[(size_t)row * HH + col];
          float xv = xp[(size_t)row * HH + col];
          v = (1.f - z) * xv + z * tanhf(v);
        }
        if (BF16OUT)
          ((ushortT*)Cout)[(size_t)row * ldc + col] = f2b(v);
        else
          ((float*)Cout)[(size_t)row * ldc + col] = v;
      }
    }
  }
}

// dual r2/z2 gemm (sigmoid), wave-granular: y=0 -> outR + gi[0:64]=r*x ; y=1 -> outZ
__global__ __launch_bounds__(64) void k_gemm_rz3(
    const ushortT* __restrict__ hid, const ushortT* __restrict__ rw2,
    const ushortT* __restrict__ zw2, const float* __restrict__ rb2,
    const float* __restrict__ zb2, float* __restrict__ outR, float* __restrict__ outZ,
    const float* __restrict__ x, ushortT* __restrict__ gi) {
  int y = blockIdx.y;
  const ushortT* A = hid + (y ? GIN : 0);
  const ushortT* W = y ? zw2 : rw2;
  const float* bias = y ? zb2 : rb2;
  float* C = y ? outZ : outR;
  constexpr int KS = GIN / 32;
  int l = threadIdx.x;
  int m0 = blockIdx.x * 16;
  int rowa = m0 + (l & 15);
  int kb = l >> 4;
  bf16x8 afr[KS];
#pragma unroll
  for (int ks = 0; ks < KS; ++ks) {
    afr[ks] = (bf16x8){0, 0, 0, 0, 0, 0, 0, 0};
    if (rowa < NN) afr[ks] = *(const bf16x8*)(A + (size_t)rowa * 384 + ks * 32 + kb * 8);
  }
  f32x4 acc[4];
#pragma unroll
  for (int n = 0; n < 4; ++n) acc[n] = (f32x4){0.f, 0.f, 0.f, 0.f};
  const ushortT* wbase = W + (size_t)(l & 15) * GIN + kb * 8;
#pragma unroll
  for (int n = 0; n < 4; ++n) {
    const ushortT* wp = wbase + (size_t)(16 * n) * GIN;
#pragma unroll
    for (int ks = 0; ks < KS; ++ks)
      acc[n] = __builtin_amdgcn_mfma_f32_16x16x32_bf16(afr[ks], *(const bf16x8*)(wp + ks * 32),
                                                       acc[n], 0, 0, 0);
  }
  int crow = m0 + (l >> 4) * 4;
  int ccol0 = l & 15;
#pragma unroll
  for (int n = 0; n < 4; ++n) {
    int col = ccol0 + n * 16;
    float bv = bias[col];
#pragma unroll
    for (int r = 0; r < 4; ++r) {
      int row = crow + r;
      if (row < NN) {
        float v = acc[n][r] + bv;
        float sig = 1.f / (1.f + expf(-v));
        C[(size_t)row * HH + col] = sig;
        if (y == 0)  // fused candin: gi[0:64] = r * x
          gi[(size_t)row * GIN + col] = f2b(sig * x[(size_t)row * HH + col]);
      }
    }
  }
}

// ------- edge combine, CSR-position-ordered, both dirs, packed f16 math -----------
__global__ __launch_bounds__(256) void k_edge3(
    const ushortT* __restrict__ cABf, const ushortT* __restrict__ cABr,
    const int4* __restrict__ pos_f, const int4* __restrict__ pos_r,
    const uint4* __restrict__ efh_f, const uint4* __restrict__ efh_r,
    const __half2* __restrict__ w1e2_f, const __half2* __restrict__ w1e2_r,
    const __half2* __restrict__ w22_f, const __half2* __restrict__ w22_r,
    float* __restrict__ s_seq, float* __restrict__ outRW,
    float* __restrict__ ws_seq, int hop) {
  int y = blockIdx.y;
  const __half2* cAB2 = (const __half2*)(y ? cABr : cABf);
  const int4* pos = y ? pos_r : pos_f;
  const uint4* efh = y ? efh_r : efh_f;
  const __half2* w1e2 = y ? w1e2_r : w1e2_f;
  const __half2* w22 = y ? w22_r : w22_f;
  __shared__ __half2 w1e2_s[8][64];
  __shared__ __half2 w22_s[4][64];
  int t = threadIdx.x;
  for (int i = t; i < 512; i += 256) w1e2_s[i >> 6][i & 63] = w1e2[i];
  if (t < 256) w22_s[t >> 6][t & 63] = w22[t];
  __syncthreads();
  int es = t >> 2, q = t & 3;
  size_t ii = (size_t)blockIdx.x * 64 + es;
  int4 pr = pos[ii];
  const __half2* cA2 = cAB2 + (size_t)pr.y * 128;
  const __half2* cB2 = cAB2 + (size_t)pr.z * 128 + 64;
  U4H8 efu;
  efu.u = efh[ii];
  __half2 efb[8];
#pragma unroll
  for (int f2v = 0; f2v < 4; ++f2v) {
    efb[2 * f2v] = __half2half2(__low2half(efu.h[f2v]));
    efb[2 * f2v + 1] = __half2half2(__high2half(efu.h[f2v]));
  }
  float pf[4] = {0.f, 0.f, 0.f, 0.f};
#pragma unroll
  for (int c = 0; c < 4; ++c) {
    int jp0 = c * 16 + q * 4;
    U4H8 ua, ub;
    ua.u = *(const uint4*)(cA2 + jp0);
    ub.u = *(const uint4*)(cB2 + jp0);
    __half2 h2v[4];
#pragma unroll
    for (int i2 = 0; i2 < 4; ++i2) h2v[i2] = __hadd2(ua.h[i2], ub.h[i2]);
#pragma unroll
    for (int f = 0; f < 8; ++f) {
      U4H8 wv;
      wv.u = *(const uint4*)(&w1e2_s[f][jp0]);
#pragma unroll
      for (int i2 = 0; i2 < 4; ++i2) h2v[i2] = __hfma2(efb[f], wv.h[i2], h2v[i2]);
    }
#pragma unroll
    for (int i2 = 0; i2 < 4; ++i2) h2v[i2] = relu2(h2v[i2]);
#pragma unroll
    for (int o = 0; o < 4; ++o) {
      U4H8 wv;
      wv.u = *(const uint4*)(&w22_s[o][jp0]);
      __half2 p2 = __hmul2(h2v[0], wv.h[0]);
      p2 = __hfma2(h2v[1], wv.h[1], p2);
      p2 = __hfma2(h2v[2], wv.h[2], p2);
      p2 = __hfma2(h2v[3], wv.h[3], p2);
      pf[o] += __low2float(p2) + __high2float(p2);
    }
  }
#pragma unroll
  for (int m = 1; m <= 2; m <<= 1) {
    pf[0] += __shfl_xor(pf[0], m, 64);
    pf[1] += __shfl_xor(pf[1], m, 64);
    pf[2] += __shfl_xor(pf[2], m, 64);
    pf[3] += __shfl_xor(pf[3], m, 64);
  }
  float pv = (q == 0) ? pf[0] : (q == 1) ? pf[1] : (q == 2) ? pf[2] : pf[3];
  if (y) {
    float sig = 1.f / (1.f + expf(-pv));
    outRW[(size_t)pr.x * (NHEAD * KHOP) + q * KHOP + hop] = sig;
    ws_seq[ii * 4 + q] = sig;
  } else {
    s_seq[ii * 4 + q] = (pv > 0.f ? pv : 0.01f * pv) * 0.25f;
  }
}

// ---- softmax/sigmoid + aggregate only -> agg_bf[N][64] (proj in k_projout) ----
__global__ __launch_bounds__(256) void k_softagg5(
    const ushortT* __restrict__ ncf, const ushortT* __restrict__ ncr,
    const float* __restrict__ s_seq, const float* __restrict__ ws_seq, int hop,
    const int* __restrict__ rp_d, const int* __restrict__ rp_s,
    const int4* __restrict__ pos_f, const int4* __restrict__ pos_r,
    ushortT* __restrict__ agg_f, ushortT* __restrict__ agg_r,
    float* __restrict__ wout) {
  int y = blockIdx.y;
  const ushortT* hn_bf = y ? ncr : ncf;
  const int* rp = y ? rp_s : rp_d;
  const int4* pos = y ? pos_r : pos_f;
  ushortT* agg = y ? agg_r : agg_f;
  __shared__ float w_s[4][64][4];
  __shared__ int ot_s[4][64];
  int t = threadIdx.x;
  int wvi = t >> 6, lane = t & 63;
  int node = blockIdx.x * 4 + wvi;
  if (node >= NN) return;
  int beg = rp[node], end = rp[node + 1];
  int deg = end - beg;
  bool small = (deg <= 64);
  float mxv = 0.f, invv = 0.f;
  int li = lane >> 2, o = lane & 3;
  if (deg > 0 && small) {
    int i0 = beg + li;
    if (y == 0) {
      int ee4[4];
      float sv[4];
#pragma unroll
      for (int u = 0; u < 4; ++u) {
        int idx = i0 + u * 16;
        bool val = idx < end;
        int4 pr = pos[val ? idx : beg];
        ee4[u] = pr.x;
        if (o == 0 && val) ot_s[wvi][li + u * 16] = pr.y * KP;
        float v = s_seq[(size_t)(val ? idx : beg) * 4 + o];
        sv[u] = val ? v : -1e30f;
      }
      float mx = fmaxf(fmaxf(sv[0], sv[1]), fmaxf(sv[2], sv[3]));
#pragma unroll
      for (int m = 4; m <= 32; m <<= 1) mx = fmaxf(mx, __shfl_xor(mx, m, 64));
      float ex[4];
      float sum = 0.f;
#pragma unroll
      for (int u = 0; u < 4; ++u) {
        ex[u] = (sv[u] > -1e29f) ? expf(sv[u] - mx) : 0.f;
        sum += ex[u];
      }
#pragma unroll
      for (int m = 4; m <= 32; m <<= 1) sum += __shfl_xor(sum, m, 64);
      float inv = 1.f / (sum + 1e-9f);
#pragma unroll
      for (int u = 0; u < 4; ++u) {
        if (i0 + u * 16 < end) {
          float wv = ex[u] * inv;
          wout[(size_t)ee4[u] * (NHEAD * KHOP) + o * KHOP + hop] = wv;
          w_s[wvi][li + u * 16][o] = wv;
        }
      }
    } else {
#pragma unroll
      for (int u = 0; u < 4; ++u) {
        int idx = i0 + u * 16;
        bool val = idx < end;
        if (val) {
          if (o == 0) {
            int4 pr = pos[idx];
            ot_s[wvi][li + u * 16] = pr.y * KP;
          }
          w_s[wvi][li + u * 16][o] = ws_seq[(size_t)idx * 4 + o];
        }
      }
    }
  } else if (deg > 0) {
    if (y == 0) {
      float mx = -1e30f;
      for (int ii = beg + li; ii < end; ii += 16)
        mx = fmaxf(mx, s_seq[(size_t)ii * 4 + o]);
#pragma unroll
      for (int m = 4; m <= 32; m <<= 1) mx = fmaxf(mx, __shfl_xor(mx, m, 64));
      float sum = 0.f;
      for (int ii = beg + li; ii < end; ii += 16)
        sum += expf(s_seq[(size_t)ii * 4 + o] - mx);
#pragma unroll
      for (int m = 4; m <= 32; m <<= 1) sum += __shfl_xor(sum, m, 64);
      float inv = 1.f / (sum + 1e-9f);
      for (int ii = beg + li; ii < end; ii += 16) {
        wout[(size_t)pos[ii].x * (NHEAD * KHOP) + o * KHOP + hop] =
            expf(s_seq[(size_t)ii * 4 + o] - mx) * inv;
      }
      mxv = mx;
      invv = inv;
    }
  }
  // aggregate
  int hd = lane >> 4;
  float acc = 0.f;
  if (small) {
    for (int ii = 0; ii < deg; ii += 8) {
#pragma unroll
      for (int u = 0; u < 8; ++u) {
        int ed = ii + u;
        int edc = (ed < deg) ? ed : 0;
        int ot = ot_s[wvi][edc];
        float w = w_s[wvi][edc][hd];
        float hv = b2f(hn_bf[(size_t)ot + lane]);
        acc += ((ed < deg) ? w : 0.f) * hv;
      }
    }
  } else {
    float mx_hd = 0.f, inv_hd = 0.f;
    if (y == 0) {
      mx_hd = __shfl(mxv, hd, 64);
      inv_hd = __shfl(invv, hd, 64);
    }
    for (int ii = beg; ii < end; ++ii) {
      int4 pr = pos[ii];
      float w;
      if (y == 0)
        w = expf(s_seq[(size_t)ii * 4 + hd] - mx_hd) * inv_hd;
      else
        w = ws_seq[(size_t)ii * 4 + hd];
      acc += w * b2f(hn_bf[(size_t)pr.y * KP + lane]);
    }
  }
  agg[(size_t)node * HH + lane] = f2b(acc);
}

// ---- proj(agg) + residual + LN/gate epilogue (MFMA, wave-granular, both dirs) ----
template <int DO_LN, int DO_GATE>
__global__ __launch_bounds__(64) void k_projout(
    const ushortT* __restrict__ agg_f, const ushortT* __restrict__ agg_r,
    const ushortT* __restrict__ pj_f, const ushortT* __restrict__ pj_r,
    float* __restrict__ h_f, float* __restrict__ h_r,
    ushortT* __restrict__ ncf_n, ushortT* __restrict__ ncr_n,
    const float* __restrict__ lnw, const float* __restrict__ lnb,
    const float* __restrict__ x, ushortT* __restrict__ gi) {
  int y = blockIdx.y;
  const ushortT* A = y ? agg_r : agg_f;
  const ushortT* W = y ? pj_r : pj_f;
  float* h = y ? h_r : h_f;
  ushortT* ncat_n = y ? ncr_n : ncf_n;
  int l = threadIdx.x;
  int m0 = blockIdx.x * 16;
  int rowa = m0 + (l & 15);
  int kb = l >> 4;
  bf16x8 afr0 = {0, 0, 0, 0, 0, 0, 0, 0}, afr1 = afr0;
  if (rowa < NN) {
    afr0 = *(const bf16x8*)(A + (size_t)rowa * HH + kb * 8);
    afr1 = *(const bf16x8*)(A + (size_t)rowa * HH + 32 + kb * 8);
  }
  f32x4 acc[4];
#pragma unroll
  for (int n = 0; n < 4; ++n) acc[n] = (f32x4){0.f, 0.f, 0.f, 0.f};
  const ushortT* wbase = W + (size_t)(l & 15) * HH + kb * 8;
#pragma unroll
  for (int n = 0; n < 4; ++n) {
    const ushortT* wp = wbase + (size_t)(16 * n) * HH;
    acc[n] = __builtin_amdgcn_mfma_f32_16x16x32_bf16(afr0, *(const bf16x8*)(wp), acc[n], 0, 0, 0);
    acc[n] = __builtin_amdgcn_mfma_f32_16x16x32_bf16(afr1, *(const bf16x8*)(wp + 32), acc[n], 0, 0, 0);
  }
  int crow = m0 + (l >> 4) * 4;
  int ccol0 = l & 15;
#pragma unroll
  for (int r = 0; r < 4; ++r) {
    int row = crow + r;
    if (row >= NN) continue;
    float hv[4];
#pragma unroll
    for (int n = 0; n < 4; ++n)
      hv[n] = h[(size_t)row * HH + ccol0 + n * 16] + acc[n][r];
    float s = hv[0] + hv[1] + hv[2] + hv[3];
#pragma unroll
    for (int m = 1; m <= 8; m <<= 1) s += __shfl_xor(s, m, 64);
    float mean = s * (1.0f / 64.0f);
    float ss = 0.f;
#pragma unroll
    for (int n = 0; n < 4; ++n) {
      float d = hv[n] - mean;
      ss += d * d;
    }
#pragma unroll
    for (int m = 1; m <= 8; m <<= 1) ss += __shfl_xor(ss, m, 64);
    float rstd = rsqrtf(ss * (1.0f / 64.0f) + 1e-5f);
#pragma unroll
    for (int n = 0; n < 4; ++n) {
      int col = ccol0 + n * 16;
      size_t g = (size_t)row * HH + col;
      h[g] = hv[n];
      if (DO_LN)
        ncat_n[(size_t)row * KP + col] = f2b((hv[n] - mean) * rstd * lnw[col] + lnb[col]);
      if (DO_GATE) {
        float xv = x[g];
        if (y == 0) {
          gi[(size_t)row * GIN + col] = f2b(xv);
          gi[(size_t)row * GIN + 64 + col] = f2b(hv[n] - xv);
        } else {
          gi[(size_t)row * GIN + 128 + col] = f2b(hv[n] - xv);
        }
      }
    }
  }
}

extern "C" void kernel_launch(void* const* d_in, const int* in_sizes, int n_in,
                              void* d_out, int out_size, void* d_ws, size_t ws_size,
                              hipStream_t stream) {
  const float* x = (const float*)d_in[0];
  const float* xs = (const float*)d_in[1];
  const int* ei = (const int*)d_in[2];
  const float* ef = (const float*)d_in[3];
  const float* fw1 = (const float*)d_in[4];
  const float* fw2 = (const float*)d_in[5];
  const float* fpj = (const float*)d_in[6];
  const float* rw1 = (const float*)d_in[7];
  const float* rw2 = (const float*)d_in[8];
  const float* rpj = (const float*)d_in[9];
  const float* lnw = (const float*)d_in[10];
  const float* lnb = (const float*)d_in[11];
  const float* r_w1 = (const float*)d_in[12];
  const float* r_b1 = (const float*)d_in[13];
  const float* r_w2 = (const float*)d_in[14];
  const float* r_b2 = (const float*)d_in[15];
  const float* z_w1 = (const float*)d_in[16];
  const float* z_b1 = (const float*)d_in[17];
  const float* z_w2 = (const float*)d_in[18];
  const float* z_b2 = (const float*)d_in[19];
  const float* c_w1 = (const float*)d_in[20];
  const float* c_b1 = (const float*)d_in[21];
  const float* c_w2 = (const float*)d_in[22];
  const float* c_b2 = (const float*)d_in[23];
  const int* srcp = ei;
  const int* dstp = ei + EE;

  float* outF = (float*)d_out;
  float* outFW = outF + (size_t)NN * HH;
  float* outRW = outFW + (size_t)EE * NHEAD * KHOP;
  float* outZ = outRW + (size_t)EE * NHEAD * KHOP;
  float* outR = outZ + (size_t)NN * HH;

  char* Wb = (char*)d_ws;
  size_t off = 0;
  auto alloc = [&](size_t bytes) -> void* {
    void* p = Wb + off;
    off += (bytes + 255) & ~(size_t)255;
    return p;
  };
  float* h_fwd = (float*)alloc((size_t)NN * HH * 4);
  float* h_rev = (float*)alloc((size_t)NN * HH * 4);
  ushortT* ncat_f0 = (ushortT*)alloc((size_t)NN * KP * 2);
  ushortT* ncat_r0 = (ushortT*)alloc((size_t)NN * KP * 2);
  ushortT* ncat_f1 = (ushortT*)alloc((size_t)NN * KP * 2);
  ushortT* ncat_r1 = (ushortT*)alloc((size_t)NN * KP * 2);
  float* s_seq = (float*)alloc((size_t)EE * NHEAD * 4);
  float* ws_seq = (float*)alloc((size_t)EE * NHEAD * 4);
  char* big = (char*)alloc((size_t)2 * NN * 256 * 2);
  ushortT* cAB_f = (ushortT*)big;          // f16 during hops
  ushortT* cAB_r = (ushortT*)(big + (size_t)NN * 256 * 2);
  ushortT* hid_bf = (ushortT*)big;         // bf16 during gating
  ushortT* gi_bf = (ushortT*)alloc((size_t)NN * GIN * 2);
  ushortT* agg_f = (ushortT*)alloc((size_t)NN * HH * 2);
  ushortT* agg_r = (ushortT*)alloc((size_t)NN * HH * 2);
  ushortT* packAB_bf = (ushortT*)alloc((size_t)4 * 256 * KP * 2);
  __half2* w1e2h = (__half2*)alloc((size_t)4 * 512 * 4);
  __half2* w22h = (__half2*)alloc((size_t)4 * 256 * 4);
  ushortT* pj_bf = (ushortT*)alloc((size_t)4 * 4096 * 2);
  ushortT* rzw1_bf = (ushortT*)alloc((size_t)384 * GIN * 2);
  ushortT* rw2_bf = (ushortT*)alloc((size_t)HH * GIN * 2);
  ushortT* zw2_bf = (ushortT*)alloc((size_t)HH * GIN * 2);
  ushortT* cw1_bf = (ushortT*)alloc((size_t)GIN * GIN * 2);
  ushortT* cw2_bf = (ushortT*)alloc((size_t)HH * GIN * 2);
  float* rz_b1 = (float*)alloc(384 * 4);
  int* rp_d = (int*)alloc((NN + 8) * 4);
  int* rp_s = (int*)alloc((NN + 8) * 4);
  int* cur2 = (int*)alloc((size_t)2 * NN * 4);
  int* cur_d = cur2;
  int* cur_s = cur2 + NN;
  int* eid_d = (int*)alloc((size_t)EE * 4);
  int* eid_s = (int*)alloc((size_t)EE * 4);
  int4* pos_f = (int4*)alloc((size_t)EE * 16);
  int4* pos_r = (int4*)alloc((size_t)EE * 16);
  uint4* efh_f = (uint4*)alloc((size_t)EE * 16);
  uint4* efh_r = (uint4*)alloc((size_t)EE * 16);

  (void)hipMemcpyAsync(h_fwd, x, (size_t)NN * HH * 4, hipMemcpyDeviceToDevice, stream);
  (void)hipMemcpyAsync(h_rev, x, (size_t)NN * HH * 4, hipMemcpyDeviceToDevice, stream);
  (void)hipMemcpyAsync(rz_b1, r_b1, GIN * 4, hipMemcpyDeviceToDevice, stream);
  (void)hipMemcpyAsync(rz_b1 + GIN, z_b1, GIN * 4, hipMemcpyDeviceToDevice, stream);

  const int EB = (EE + 255) / 256, NW = (NN + 3) / 4;
  const int PB = (PACKN + 255) / 256;

  // weight repacks
  dim3 gPack(PB, 4);
  k_pack_bf<<<gPack, 256, 0, stream>>>(fw1, rw1, fw2, rw2, fpj, rpj, packAB_bf,
                                       w1e2h, w22h, pj_bf);
  k_cvt6<<<(3 * CW1 + 3 * CW2 + 255) / 256, 256, 0, stream>>>(
      r_w1, z_w1, c_w1, r_w2, z_w2, c_w2, rzw1_bf, cw1_bf, rw2_bf, zw2_bf, cw2_bf);

  // CSR build (both directions)
  (void)hipMemsetAsync(cur2, 0, (size_t)2 * NN * 4, stream);
  k_histo2<<<EB, 256, 0, stream>>>(srcp, dstp, cur_s, cur_d);
  k_scan2<<<2, 1024, 0, stream>>>(cur_d, cur_s, rp_d, rp_s);
  (void)hipMemsetAsync(cur2, 0, (size_t)2 * NN * 4, stream);
  k_scatter2<<<EB, 256, 0, stream>>>(srcp, dstp, rp_s, rp_d, cur_s, cur_d, eid_s, eid_d);
  k_sortseg2<<<(2 * NN + 3) / 4, 256, 0, stream>>>(rp_d, rp_s, eid_d, eid_s);
  k_mkpos2<<<EB, 256, 0, stream>>>(eid_d, eid_s, srcp, dstp, ef, pos_f, pos_r, efh_f, efh_r);

  // initial LN (h = x for both chains)
  k_ln_init<<<NW, 256, 0, stream>>>(x, xs, lnw, lnb, ncat_f0, ncat_r0, ncat_f1, ncat_r1);

  const int MB64 = (NN + 63) / 64;   // 391
  const int MB16 = (NN + 15) / 16;   // 1563
  dim3 gProj(MB64, 8), gEdge(EE / 64, 2), gAgg(NW, 2), gPO(MB16, 2);
  for (int k = 0; k < KHOP; ++k) {
    const ushortT* nf = k ? ncat_f1 : ncat_f0;
    const ushortT* nr = k ? ncat_r1 : ncat_r0;
    k_proj2<<<gProj, 256, 0, stream>>>(nf, nr,
                                       packAB_bf + (size_t)k * 256 * KP,
                                       packAB_bf + (size_t)(2 + k) * 256 * KP,
                                       cAB_f, cAB_r);
    k_edge3<<<gEdge, 256, 0, stream>>>(cAB_f, cAB_r, pos_f, pos_r, efh_f, efh_r,
                                       w1e2h + (size_t)k * 512,
                                       w1e2h + (size_t)(2 + k) * 512,
                                       w22h + (size_t)k * 256,
                                       w22h + (size_t)(2 + k) * 256,
                                       s_seq, outRW, ws_seq, k);
    k_softagg5<<<gAgg, 256, 0, stream>>>(nf, nr, s_seq, ws_seq, k, rp_d, rp_s,
                                         pos_f, pos_r, agg_f, agg_r, outFW);
    if (k == 0)
      k_projout<1, 0><<<gPO, 64, 0, stream>>>(
          agg_f, agg_r, pj_bf + (size_t)k * 4096, pj_bf + (size_t)(2 + k) * 4096,
          h_fwd, h_rev, ncat_f1, ncat_r1, lnw, lnb, x, gi_bf);
    else
      k_projout<0, 1><<<gPO, 64, 0, stream>>>(
          agg_f, agg_r, pj_bf + (size_t)k * 4096, pj_bf + (size_t)(2 + k) * 4096,
          h_fwd, h_rev, ncat_f1, ncat_r1, lnw, lnb, x, gi_bf);
  }

  // gating (wave-granular grids for occupancy)
  dim3 gRZ1(MB16, 6), gRZ2(MB16, 2), gC1(MB16, 3), gF(MB16, 1);
  k_gemm3<1, 1, GIN><<<gRZ1, 64, 0, stream>>>(gi_bf, GIN, rzw1_bf, rz_b1, hid_bf,
                                              384, NN, nullptr, nullptr);
  k_gemm_rz3<<<gRZ2, 64, 0, stream>>>(hid_bf, rw2_bf, zw2_bf, r_b2, z_b2, outR, outZ,
                                      x, gi_bf);
  k_gemm3<1, 1, GIN><<<gC1, 64, 0, stream>>>(gi_bf, GIN, cw1_bf, c_b1, hid_bf, GIN,
                                             NN, nullptr, nullptr);
  k_gemm3<5, 0, GIN><<<gF, 64, 0, stream>>>(hid_bf, GIN, cw2_bf, c_b2, outF, HH, NN,
                                            outZ, x);
}